// Round 1
// baseline (887.336 us; speedup 1.0000x reference)
//
#include <hip/hip_runtime.h>
#include <hip/hip_bf16.h>

typedef __bf16 bf16_t;
typedef bf16_t bf16x2 __attribute__((ext_vector_type(2)));
typedef bf16_t bf16x4 __attribute__((ext_vector_type(4)));
typedef bf16_t bf16x8 __attribute__((ext_vector_type(8)));
typedef float f32x2 __attribute__((ext_vector_type(2)));
typedef float f32x4 __attribute__((ext_vector_type(4)));

static constexpr int NCn = 100000;
static constexpr int NPn = 50000;
static constexpr int NE  = 500000;

// Dual-dtype input load: inputs may be fp32 or bf16 (runtime-detected flag).
__device__ __forceinline__ float ldin(const void* p, size_t i, int fp32) {
    return fp32 ? ((const float*)p)[i] : (float)((const bf16_t*)p)[i];
}

__global__ __launch_bounds__(64) void detect_dtype(const void* x, int* flag) {
    const bf16_t* xb = (const bf16_t*)x;
    int lane = threadIdx.x;
    int bad = 0;
    for (int i = lane; i < 512; i += 64) {
        float v = (float)xb[i];
        if (!(v > -1e4f && v < 1e4f)) bad = 1;
    }
    unsigned long long m = __ballot(bad);
    if (lane == 0) flag[0] = (m != 0ull) ? 1 : 0;
}

// ---- tiny utility kernels (replace hipMemsetAsync / hipMemcpyAsync) ---------
__global__ __launch_bounds__(256) void zero_int(int* __restrict__ p, int n) {
    int i = blockIdx.x * 256 + threadIdx.x;
    if (i < n) p[i] = 0;
}
__global__ __launch_bounds__(256) void copy_int(const int* __restrict__ s,
                                                int* __restrict__ d, int n) {
    int i = blockIdx.x * 256 + threadIdx.x;
    if (i < n) d[i] = s[i];
}

// Fold dst-projection against attention vector: V[k,h] = sum_c W[k,h*C+c]*att[h,c]
__global__ __launch_bounds__(256) void prep_V(const int* __restrict__ flag,
                                              const void* w1bd, const void* a1bd,
                                              const void* w1rd, const void* a1rd,
                                              const void* w2bd, const void* a2bd,
                                              const void* w2rd, const void* a2rd,
                                              float* V1bd, float* V1rd,
                                              float* V2bd, float* V2rd) {
    int fp32 = flag[0];
    int t = threadIdx.x;
    for (int idx = t; idx < 256; idx += 256) {          // V1bd: k<128, h<2
        int k = idx >> 1, h = idx & 1;
        float s = 0.f;
        for (int c = 0; c < 64; ++c)
            s += ldin(w1bd, (size_t)k * 128 + h * 64 + c, fp32) * ldin(a1bd, h * 64 + c, fp32);
        V1bd[k * 2 + h] = s;
    }
    for (int idx = t; idx < 512; idx += 256) {          // V1rd: k<256, h<2
        int k = idx >> 1, h = idx & 1;
        float s = 0.f;
        for (int c = 0; c < 64; ++c)
            s += ldin(w1rd, (size_t)k * 128 + h * 64 + c, fp32) * ldin(a1rd, h * 64 + c, fp32);
        V1rd[k * 2 + h] = s;
    }
    for (int k = t; k < 128; k += 256) {                // V2bd
        float s = 0.f;
        for (int c = 0; c < 64; ++c)
            s += ldin(w2bd, (size_t)k * 64 + c, fp32) * ldin(a2bd, c, fp32);
        V2bd[k] = s;
    }
    for (int k = t; k < 128; k += 256) {                // V2rd
        float s = 0.f;
        for (int c = 0; c < 64; ++c)
            s += ldin(w2rd, (size_t)k * 64 + c, fp32) * ldin(a2rd, c, fp32);
        V2rd[k] = s;
    }
}

// Transpose + convert weight W[K][N] (input dtype) -> Wt[N][K] bf16.
__global__ __launch_bounds__(256) void prep_w(const void* __restrict__ W,
                                              bf16_t* __restrict__ Wt,
                                              int N, int ks,
                                              const int* __restrict__ flag) {
    int fp32 = flag[0];
    int idx = blockIdx.x * 256 + threadIdx.x;
    int K = 1 << ks;
    int n = idx >> ks, k = idx & (K - 1);
    if (n < N) Wt[idx] = (bf16_t)ldin(W, (size_t)k * N + n, fp32);
}

// Convert X[M][K] (flag dtype) -> bf16, fused with ad[m,h] = X[m,:] @ V[:,h].
template<int K>
__global__ __launch_bounds__(256) void cvt_rows(const void* __restrict__ X,
                                                bf16_t* __restrict__ Xb,
                                                const float* __restrict__ V,
                                                float* __restrict__ ad,
                                                int M, const int* __restrict__ flag) {
    constexpr int EPL = K / 64;
    int fp32 = flag[0];
    int wid = (blockIdx.x * 256 + threadIdx.x) >> 6;
    int lane = threadIdx.x & 63;
    if (wid >= M) return;
    size_t base = (size_t)wid * K + lane * EPL;
    float x[EPL];
    if constexpr (EPL == 4) {
        if (fp32) { f32x4 t = *(const f32x4*)((const float*)X + base);
#pragma unroll
            for (int j = 0; j < 4; ++j) x[j] = t[j];
        } else { bf16x4 t = *(const bf16x4*)((const bf16_t*)X + base);
#pragma unroll
            for (int j = 0; j < 4; ++j) x[j] = (float)t[j];
        }
        bf16x4 o;
#pragma unroll
        for (int j = 0; j < 4; ++j) o[j] = (bf16_t)x[j];
        *(bf16x4*)(Xb + base) = o;
    } else {
        if (fp32) { f32x2 t = *(const f32x2*)((const float*)X + base);
#pragma unroll
            for (int j = 0; j < 2; ++j) x[j] = t[j];
        } else { bf16x2 t = *(const bf16x2*)((const bf16_t*)X + base);
#pragma unroll
            for (int j = 0; j < 2; ++j) x[j] = (float)t[j];
        }
        bf16x2 o;
#pragma unroll
        for (int j = 0; j < 2; ++j) o[j] = (bf16_t)x[j];
        *(bf16x2*)(Xb + base) = o;
    }
    float a0 = 0.f, a1 = 0.f;
#pragma unroll
    for (int j = 0; j < EPL; ++j) {
        int k = lane * EPL + j;
        a0 += x[j] * V[k * 2];
        a1 += x[j] * V[k * 2 + 1];
    }
    for (int off = 32; off; off >>= 1) {
        a0 += __shfl_down(a0, off);
        a1 += __shfl_down(a1, off);
    }
    if (lane == 0) { ad[(size_t)wid * 2] = a0; ad[(size_t)wid * 2 + 1] = a1; }
}

// ---------------- CSR build: histogram -> hierarchical scan -> scatter --------
__global__ __launch_bounds__(256) void hist_k(const int* __restrict__ dst,
                                              int* __restrict__ cnt, int E) {
    int e = blockIdx.x * 256 + threadIdx.x;
    if (e < E) atomicAdd(&cnt[dst[e]], 1);
}

__global__ __launch_bounds__(256) void scan_blocks(const int* __restrict__ cnt,
                                                   int* __restrict__ rs,
                                                   int* __restrict__ bsum, int N) {
    int t = threadIdx.x, b = blockIdx.x;
    int base = b * 1024 + t * 4;
    int c[4];
#pragma unroll
    for (int k = 0; k < 4; ++k) { int i = base + k; c[k] = (i < N) ? cnt[i] : 0; }
    int tsum = c[0] + c[1] + c[2] + c[3];
    __shared__ int sd[256];
    sd[t] = tsum;
    __syncthreads();
    for (int off = 1; off < 256; off <<= 1) {
        int x = (t >= off) ? sd[t - off] : 0;
        __syncthreads();
        sd[t] += x;
        __syncthreads();
    }
    int run = sd[t] - tsum;
#pragma unroll
    for (int k = 0; k < 4; ++k) { int i = base + k; if (i < N) rs[i] = run; run += c[k]; }
    if (t == 255) bsum[b] = sd[255];
}

__global__ __launch_bounds__(128) void scan_bsum(int* bsum, int nb) {
    int t = threadIdx.x;
    __shared__ int sd[128];
    int v = (t < nb) ? bsum[t] : 0;
    sd[t] = v;
    __syncthreads();
    for (int off = 1; off < 128; off <<= 1) {
        int x = (t >= off) ? sd[t - off] : 0;
        __syncthreads();
        sd[t] += x;
        __syncthreads();
    }
    if (t < nb) bsum[t] = sd[t] - v;
}

__global__ __launch_bounds__(256) void scan_add(int* __restrict__ rs,
                                                const int* __restrict__ bsum,
                                                int N, int E) {
    int i = blockIdx.x * 256 + threadIdx.x;
    if (i < N) rs[i] += bsum[i >> 10];
    if (i == 0) rs[N] = E;
}

__global__ __launch_bounds__(256) void scatter_k(const int* __restrict__ dst,
                                                 const int* __restrict__ nbr,
                                                 int* __restrict__ cur,
                                                 int* __restrict__ srcs, int E) {
    int e = blockIdx.x * 256 + threadIdx.x;
    if (e >= E) return;
    int pos = atomicAdd(&cur[dst[e]], 1);
    srcs[pos] = nbr[e];
}

// ---------------- LDS-free GEMM: C[M,N] = A[M,K] @ Wt[N,K]^T, all bf16 -------
template<int K>
__global__ __launch_bounds__(256) void gemm_nl(const bf16_t* __restrict__ A,
                                               const bf16_t* __restrict__ Wt,
                                               bf16_t* __restrict__ C,
                                               int M, int N) {
    const int w = threadIdx.x >> 6;
    const int lane = threadIdx.x & 63;
    const int lm = lane & 15;
    const int lq = lane >> 4;
    const int n0 = blockIdx.y * 64;
    const int r0 = blockIdx.x * 128 + w * 32;
    int ra0 = r0 + lm;       if (ra0 > M - 1) ra0 = M - 1;
    int ra1 = r0 + 16 + lm;  if (ra1 > M - 1) ra1 = M - 1;
    const bf16_t* A0 = A + (size_t)ra0 * K + lq * 8;
    const bf16_t* A1 = A + (size_t)ra1 * K + lq * 8;
    const bf16_t* B0 = Wt + (size_t)(n0 + lm) * K + lq * 8;
    f32x4 acc[2][4] = {};
#pragma unroll
    for (int kt = 0; kt < K / 32; ++kt) {
        bf16x8 a0 = *(const bf16x8*)(A0 + kt * 32);
        bf16x8 a1 = *(const bf16x8*)(A1 + kt * 32);
#pragma unroll
        for (int nt = 0; nt < 4; ++nt) {
            bf16x8 b = *(const bf16x8*)(B0 + (size_t)nt * 16 * K + kt * 32);
            acc[0][nt] = __builtin_amdgcn_mfma_f32_16x16x32_bf16(a0, b, acc[0][nt], 0, 0, 0);
            acc[1][nt] = __builtin_amdgcn_mfma_f32_16x16x32_bf16(a1, b, acc[1][nt], 0, 0, 0);
        }
    }
#pragma unroll
    for (int rt = 0; rt < 2; ++rt) {
        const int crow0 = r0 + rt * 16 + lq * 4;
#pragma unroll
        for (int nt = 0; nt < 4; ++nt) {
            int col = n0 + nt * 16 + lm;
#pragma unroll
            for (int i = 0; i < 4; ++i) {
                int r = crow0 + i;
                if (r < M) C[(size_t)r * N + col] = (bf16_t)acc[rt][nt][i];
            }
        }
    }
}

// ---------------- a_s = sum_c h[n,h,c]*att[h,c] : one wave per node ----------
__global__ __launch_bounds__(256) void att_dot(const bf16_t* __restrict__ Hb,
                                               const void* __restrict__ att,
                                               float* __restrict__ out,
                                               int Nn, int HD, int H,
                                               const int* __restrict__ flag) {
    int fp32 = flag[0];
    int wid = (blockIdx.x * 256 + threadIdx.x) >> 6;
    int lane = threadIdx.x & 63;
    if (wid >= Nn) return;
    const bf16_t* hp = Hb + (size_t)wid * HD;
    float p0 = (float)hp[lane] * ldin(att, lane, fp32);
    float p1 = 0.f;
    if (HD > 64) p1 = (float)hp[64 + lane] * ldin(att, 64 + lane, fp32);
    for (int off = 32; off; off >>= 1) {
        p0 += __shfl_down(p0, off);
        p1 += __shfl_down(p1, off);
    }
    if (lane == 0) {
        out[(size_t)wid * H] = p0;
        if (H == 2) out[(size_t)wid * H + 1] = p1;
    }
}

// ---------------- fused segment-softmax + aggregate --------------------------
// Fast path (deg<=64): srcs + exp(alpha) cached in registers during the
// lane-parallel denominator pass; accumulate phase processes 4 edges per
// iteration (16 lanes x bf16x8/bf16x4 per edge) with weights broadcast via
// shfl -> no per-edge re-gather, no redundant exp, deg/4 serial chain.
// MODE 0 additionally emits ad2[wid] = relu(out) . V2  (fused gemv_att).
template<int HD, int MODE>
__global__ __launch_bounds__(256) void aggregate(const int* __restrict__ rs,
                                                 const int* __restrict__ srcs,
                                                 const float* __restrict__ as_,
                                                 const float* __restrict__ ad_,
                                                 const bf16_t* __restrict__ Hm,
                                                 const void* __restrict__ bias,
                                                 void* __restrict__ outb, size_t obase,
                                                 const float* __restrict__ V2,
                                                 float* __restrict__ ad2,
                                                 int Nd, const int* __restrict__ flag) {
    constexpr int NH = HD / 64;       // 2 (layer1) or 1 (layer2)
    constexpr int CPL = HD / 16;      // channels per lane in fast path: 8 or 4
    int wid = (blockIdx.x * 256 + threadIdx.x) >> 6;
    int lane = threadIdx.x & 63;
    if (wid >= Nd) return;
    int start = rs[wid], end = rs[wid + 1];
    int deg = end - start;
    float ad0 = ad_[(size_t)wid * NH];
    float ad1 = (NH == 2) ? ad_[(size_t)wid * NH + 1] : 0.f;
    int fp32 = flag[0];

    if (deg <= 64) {
        // ---- phase 1: lane-parallel scores, kept in registers ----
        int s = 0; float e0 = 0.f, e1 = 0.f;
        if (lane < deg) {
            s = srcs[start + lane];
            if (NH == 2) {
                f32x2 a = *(const f32x2*)(as_ + (size_t)s * 2);
                float v0 = a[0] + ad0; v0 = v0 > 0.f ? v0 : 0.2f * v0;
                float v1 = a[1] + ad1; v1 = v1 > 0.f ? v1 : 0.2f * v1;
                e0 = __expf(fminf(v0, 60.f));
                e1 = __expf(fminf(v1, 60.f));
            } else {
                float v0 = as_[s] + ad0; v0 = v0 > 0.f ? v0 : 0.2f * v0;
                e0 = __expf(fminf(v0, 60.f));
            }
        }
        float den0 = e0, den1 = e1;
        for (int off = 32; off; off >>= 1) {
            den0 += __shfl_down(den0, off);
            if (NH == 2) den1 += __shfl_down(den1, off);
        }
        den0 = __shfl(den0, 0);
        float inv0 = 1.f / (den0 + 1e-16f), inv1 = 0.f;
        if (NH == 2) { den1 = __shfl(den1, 0); inv1 = 1.f / (den1 + 1e-16f); }

        // ---- phase 2: 4 edges in parallel (quarter-waves), shfl'd weights ----
        const int q = lane >> 4;
        const int l15 = lane & 15;
        float acc[CPL];
#pragma unroll
        for (int i = 0; i < CPL; ++i) acc[i] = 0.f;
#pragma unroll 2
        for (int j0 = 0; j0 < deg; j0 += 4) {
            int jj = j0 + q;
            int sj = __shfl(s, jj);
            float w = __shfl(e0, jj) * inv0;
            if (NH == 2) {
                float w1 = __shfl(e1, jj) * inv1;
                if (l15 >= 8) w = w1;   // channels 64..127 -> head 1
            }
            if (jj < deg) {
                if constexpr (HD == 128) {
                    bf16x8 hv = *(const bf16x8*)(Hm + (size_t)sj * 128 + l15 * 8);
#pragma unroll
                    for (int i = 0; i < 8; ++i) acc[i] += (float)hv[i] * w;
                } else {
                    bf16x4 hv = *(const bf16x4*)(Hm + (size_t)sj * 64 + l15 * 4);
#pragma unroll
                    for (int i = 0; i < 4; ++i) acc[i] += (float)hv[i] * w;
                }
            }
        }
        // combine quarter partials -> every lane has totals for its l15 group
#pragma unroll
        for (int i = 0; i < CPL; ++i) {
            acc[i] += __shfl_xor(acc[i], 16);
            acc[i] += __shfl_xor(acc[i], 32);
        }
        const int c0 = l15 * CPL;
        if constexpr (MODE == 0) {
            float o[CPL];
            float pp = 0.f;
#pragma unroll
            for (int i = 0; i < CPL; ++i) {
                o[i] = fmaxf(acc[i] + ldin(bias, c0 + i, fp32), 0.f);
                pp += o[i] * V2[c0 + i];
            }
            if (lane < 16) {
                bf16x8 ov;
#pragma unroll
                for (int i = 0; i < 8; ++i) ov[i] = (bf16_t)o[i];
                *(bf16x8*)((bf16_t*)outb + (size_t)wid * 128 + c0) = ov;
            }
            for (int off = 8; off; off >>= 1) pp += __shfl_down(pp, off);
            if (lane == 0) ad2[wid] = pp;
        } else {
            if (lane < 16) {
                if (fp32) {
                    f32x4 ov;
#pragma unroll
                    for (int i = 0; i < 4; ++i) ov[i] = acc[i] + ldin(bias, c0 + i, fp32);
                    *(f32x4*)((float*)outb + obase + (size_t)wid * 64 + c0) = ov;
                } else {
                    bf16x4 ov;
#pragma unroll
                    for (int i = 0; i < 4; ++i) ov[i] = (bf16_t)(acc[i] + ldin(bias, c0 + i, fp32));
                    *(bf16x4*)((bf16_t*)outb + obase + (size_t)wid * 64 + c0) = ov;
                }
            }
        }
        return;
    }

    // ---------------- slow path: deg > 64 (rare) ----------------
    float den0 = 0.f, den1 = 0.f;
    for (int i = start + lane; i < end; i += 64) {
        int s = srcs[i];
        float v0 = as_[(size_t)s * NH] + ad0;
        v0 = v0 > 0.f ? v0 : 0.2f * v0;
        den0 += __expf(fminf(v0, 60.f));
        if (NH == 2) {
            float v1 = as_[(size_t)s * NH + 1] + ad1;
            v1 = v1 > 0.f ? v1 : 0.2f * v1;
            den1 += __expf(fminf(v1, 60.f));
        }
    }
    for (int off = 32; off; off >>= 1) {
        den0 += __shfl_down(den0, off);
        if (NH == 2) den1 += __shfl_down(den1, off);
    }
    den0 = __shfl(den0, 0);
    float inv0 = 1.f / (den0 + 1e-16f), inv1 = 0.f;
    if (NH == 2) { den1 = __shfl(den1, 0); inv1 = 1.f / (den1 + 1e-16f); }

    float acc0 = 0.f, acc1 = 0.f;
    for (int j = start; j < end; ++j) {
        int s = srcs[j];
        if (NH == 2) {
            float v0 = as_[(size_t)s * 2] + ad0;
            v0 = v0 > 0.f ? v0 : 0.2f * v0;
            float v1 = as_[(size_t)s * 2 + 1] + ad1;
            v1 = v1 > 0.f ? v1 : 0.2f * v1;
            float e0 = __expf(fminf(v0, 60.f)) * inv0;
            float e1 = __expf(fminf(v1, 60.f)) * inv1;
            float w = (lane >> 5) ? e1 : e0;
            bf16x2 hv = *(const bf16x2*)(Hm + (size_t)s * 128 + 2 * lane);
            acc0 += (float)hv[0] * w;
            acc1 += (float)hv[1] * w;
        } else {
            float v0 = as_[s] + ad0;
            v0 = v0 > 0.f ? v0 : 0.2f * v0;
            float w = __expf(fminf(v0, 60.f)) * inv0;
            acc0 += (float)Hm[(size_t)s * 64 + lane] * w;
        }
    }
    if (NH == 2) {
        int c0 = 2 * lane;
        float o0 = fmaxf(acc0 + ldin(bias, c0, fp32), 0.f);
        float o1 = fmaxf(acc1 + ldin(bias, c0 + 1, fp32), 0.f);
        bf16x2 ov;
        ov[0] = (bf16_t)o0;
        ov[1] = (bf16_t)o1;
        *(bf16x2*)((bf16_t*)outb + (size_t)wid * 128 + c0) = ov;
        if constexpr (MODE == 0) {
            float pp = o0 * V2[c0] + o1 * V2[c0 + 1];
            for (int off = 32; off; off >>= 1) pp += __shfl_down(pp, off);
            if (lane == 0) ad2[wid] = pp;
        }
    } else {
        float o = acc0 + ldin(bias, lane, fp32);
        size_t oi = obase + (size_t)wid * 64 + lane;
        if (fp32) ((float*)outb)[oi] = o;
        else      ((bf16_t*)outb)[oi] = (bf16_t)o;
    }
}

extern "C" void kernel_launch(void* const* d_in, const int* in_sizes, int n_in,
                              void* d_out, int out_size, void* d_ws, size_t ws_size,
                              hipStream_t stream) {
    const void* xc = d_in[0];
    const void* xp = d_in[1];
    const int* esrc = (const int*)d_in[2];   // customer ids
    const int* edst = (const int*)d_in[3];   // product ids
    const void* w1b_src = d_in[4];
    const void* w1b_dst = d_in[5];
    const void* a1b_src = d_in[6];
    const void* a1b_dst = d_in[7];
    const void* b1b     = d_in[8];
    const void* w1r_src = d_in[9];
    const void* w1r_dst = d_in[10];
    const void* a1r_src = d_in[11];
    const void* a1r_dst = d_in[12];
    const void* b1r     = d_in[13];
    const void* w2b_src = d_in[14];
    const void* w2b_dst = d_in[15];
    const void* a2b_src = d_in[16];
    const void* a2b_dst = d_in[17];
    const void* b2b     = d_in[18];
    const void* w2r_src = d_in[19];
    const void* w2r_dst = d_in[20];
    const void* a2r_src = d_in[21];
    const void* a2r_dst = d_in[22];
    const void* b2r     = d_in[23];

    // -------- workspace layout: NO aliasing (~168 MB, ws proven >= 199 MB) ----
    char* p = (char*)d_ws;
    auto alloc = [&](size_t nbytes) {
        char* r = p;
        p += (nbytes + 255) & ~(size_t)255;
        return r;
    };
    int* flag   = (int*)alloc(256);
    float* V1bd = (float*)alloc(256 * 4);
    float* V1rd = (float*)alloc(512 * 4);
    float* V2bd = (float*)alloc(128 * 4);
    float* V2rd = (float*)alloc(128 * 4);
    bf16_t* Wt1b = (bf16_t*)alloc(128 * 256 * 2);
    bf16_t* Wt1r = (bf16_t*)alloc(128 * 128 * 2);
    bf16_t* Wt2b = (bf16_t*)alloc(64 * 128 * 2);
    bf16_t* Wt2r = (bf16_t*)alloc(64 * 128 * 2);
    float* as_s = (float*)alloc((size_t)NCn * 2 * 4);
    float* ad_b = (float*)alloc((size_t)NPn * 2 * 4);
    float* ad_r = (float*)alloc((size_t)NCn * 2 * 4);
    float* ad2_b = (float*)alloc((size_t)NPn * 4);
    float* ad2_r = (float*)alloc((size_t)NCn * 4);
    int* rsB    = (int*)alloc((size_t)(NPn + 1) * 4);
    int* rsR    = (int*)alloc((size_t)(NCn + 1) * 4);
    int* srcsB  = (int*)alloc((size_t)NE * 4);
    int* srcsR  = (int*)alloc((size_t)NE * 4);
    int* cntB   = (int*)alloc((size_t)NPn * 4);
    int* cntR   = (int*)alloc((size_t)NCn * 4);
    int* bsum   = (int*)alloc(128 * 4);
    bf16_t* xcb = (bf16_t*)alloc((size_t)NCn * 256 * 2);
    bf16_t* xpb = (bf16_t*)alloc((size_t)NPn * 128 * 2);
    bf16_t* Hc  = (bf16_t*)alloc((size_t)NCn * 128 * 2);
    bf16_t* Hp  = (bf16_t*)alloc((size_t)NPn * 128 * 2);
    bf16_t* c1  = (bf16_t*)alloc((size_t)NCn * 128 * 2);
    bf16_t* p1  = (bf16_t*)alloc((size_t)NPn * 128 * 2);
    bf16_t* Hc2 = (bf16_t*)alloc((size_t)NCn * 64 * 2);
    bf16_t* Hp2 = (bf16_t*)alloc((size_t)NPn * 64 * 2);

    const dim3 blk(256);
    const int gE = (NE + 255) / 256;
    const int sbP = (NPn + 1023) / 1024;
    const int sbR = (NCn + 1023) / 1024;
    const int gmC = (NCn + 127) / 128;
    const int gmP = (NPn + 127) / 128;
    const int gNP = (NPn + 255) / 256;
    const int gNC = (NCn + 255) / 256;

    detect_dtype<<<1, 64, 0, stream>>>(xc, flag);
    prep_V<<<1, 256, 0, stream>>>(flag, w1b_dst, a1b_dst, w1r_dst, a1r_dst,
                                  w2b_dst, a2b_dst, w2r_dst, a2r_dst,
                                  V1bd, V1rd, V2bd, V2rd);
    prep_w<<<128, blk, 0, stream>>>(w1b_src, Wt1b, 128, 8, flag);
    prep_w<<<64,  blk, 0, stream>>>(w1r_src, Wt1r, 128, 7, flag);
    prep_w<<<32,  blk, 0, stream>>>(w2b_src, Wt2b, 64, 7, flag);
    prep_w<<<32,  blk, 0, stream>>>(w2r_src, Wt2r, 64, 7, flag);

    // -------- CSR build dir b (dst = product) --------
    zero_int<<<gNP, blk, 0, stream>>>(cntB, NPn);
    hist_k<<<gE, blk, 0, stream>>>(edst, cntB, NE);
    scan_blocks<<<sbP, blk, 0, stream>>>(cntB, rsB, bsum, NPn);
    scan_bsum<<<1, 128, 0, stream>>>(bsum, sbP);
    scan_add<<<gNP + 1, blk, 0, stream>>>(rsB, bsum, NPn, NE);
    copy_int<<<gNP, blk, 0, stream>>>(rsB, cntB, NPn);
    scatter_k<<<gE, blk, 0, stream>>>(edst, esrc, cntB, srcsB, NE);

    // -------- CSR build dir r (dst = customer) --------
    zero_int<<<gNC, blk, 0, stream>>>(cntR, NCn);
    hist_k<<<gE, blk, 0, stream>>>(esrc, cntR, NE);
    scan_blocks<<<sbR, blk, 0, stream>>>(cntR, rsR, bsum, NCn);
    scan_bsum<<<1, 128, 0, stream>>>(bsum, sbR);
    scan_add<<<gNC + 1, blk, 0, stream>>>(rsR, bsum, NCn, NE);
    copy_int<<<gNC, blk, 0, stream>>>(rsR, cntR, NCn);
    scatter_k<<<gE, blk, 0, stream>>>(esrc, edst, cntR, srcsR, NE);

    // -------- convert inputs to bf16 + fused L1 dst scores --------
    cvt_rows<256><<<(NCn + 3) / 4, blk, 0, stream>>>(xc, xcb, V1rd, ad_r, NCn, flag);
    cvt_rows<128><<<(NPn + 3) / 4, blk, 0, stream>>>(xp, xpb, V1bd, ad_b, NPn, flag);

    // -------- layer 1 src projections --------
    gemm_nl<256><<<dim3(gmC, 2), blk, 0, stream>>>(xcb, Wt1b, Hc, NCn, 128);
    gemm_nl<128><<<dim3(gmP, 2), blk, 0, stream>>>(xpb, Wt1r, Hp, NPn, 128);

    // ---- L1 dir b (customer -> product) -> p1 (+ fused ad2_b = p1.V2bd) ----
    att_dot<<<(NCn + 3) / 4, blk, 0, stream>>>(Hc, a1b_src, as_s, NCn, 128, 2, flag);
    aggregate<128, 0><<<(NPn + 3) / 4, blk, 0, stream>>>(rsB, srcsB, as_s, ad_b, Hc, b1b, p1, 0, V2bd, ad2_b, NPn, flag);

    // ---- L1 dir r (product -> customer) -> c1 (+ fused ad2_r = c1.V2rd) ----
    att_dot<<<(NPn + 3) / 4, blk, 0, stream>>>(Hp, a1r_src, as_s, NPn, 128, 2, flag);
    aggregate<128, 0><<<(NCn + 3) / 4, blk, 0, stream>>>(rsR, srcsR, as_s, ad_r, Hp, b1r, c1, 0, V2rd, ad2_r, NCn, flag);

    // -------- layer 2 src projections --------
    gemm_nl<128><<<dim3(gmC, 1), blk, 0, stream>>>(c1, Wt2b, Hc2, NCn, 64);
    gemm_nl<128><<<dim3(gmP, 1), blk, 0, stream>>>(p1, Wt2r, Hp2, NPn, 64);

    // ---- L2 dir b -> p2 (second half of d_out) ----
    att_dot<<<(NCn + 3) / 4, blk, 0, stream>>>(Hc2, a2b_src, as_s, NCn, 64, 1, flag);
    aggregate<64, 1><<<(NPn + 3) / 4, blk, 0, stream>>>(rsB, srcsB, as_s, ad2_b, Hc2, b2b, d_out, (size_t)NCn * 64, nullptr, nullptr, NPn, flag);

    // ---- L2 dir r -> c2 (first half of d_out) ----
    att_dot<<<(NPn + 3) / 4, blk, 0, stream>>>(Hp2, a2r_src, as_s, NPn, 64, 1, flag);
    aggregate<64, 1><<<(NCn + 3) / 4, blk, 0, stream>>>(rsR, srcsR, as_s, ad2_r, Hp2, b2r, d_out, 0, nullptr, nullptr, NCn, flag);
}